// Round 1
// baseline (635.101 us; speedup 1.0000x reference)
//
#include <hip/hip_runtime.h>
#include <math.h>

#define BS   8192
#define DD   768
#define NC   64
#define NCL  500
#define CS   100
#define NY   1000
#define EPSN 1e-12f

// ---------------- cluster_mean: [500,100,768] -> [500,768] ----------------
__global__ __launch_bounds__(256) void k_cmean(const float* __restrict__ clusters,
                                               float* __restrict__ cm) {
    int idx = blockIdx.x * 256 + threadIdx.x;          // over 500*768/4 float4s
    if (idx >= NCL * DD / 4) return;
    int r  = idx / (DD / 4);
    int d4 = idx % (DD / 4);
    const float4* base = (const float4*)(clusters + (size_t)r * CS * DD) + d4;
    float4 acc = {0.f, 0.f, 0.f, 0.f};
    for (int s = 0; s < CS; ++s) {
        float4 v = base[(size_t)s * (DD / 4)];
        acc.x += v.x; acc.y += v.y; acc.z += v.z; acc.w += v.w;
    }
    const float sc = 1.0f / CS;
    acc.x *= sc; acc.y *= sc; acc.z *= sc; acc.w *= sc;
    ((float4*)cm)[idx] = acc;
}

// ---------------- gram = C^T C  [64,64] ----------------
__global__ __launch_bounds__(256) void k_gram(const float* __restrict__ C,
                                              float* __restrict__ gram) {
    int j   = blockIdx.x;           // 0..63
    int i   = threadIdx.x & 63;
    int seg = threadIdx.x >> 6;     // 0..3
    float p = 0.f;
    for (int k = seg * 192; k < seg * 192 + 192; ++k)
        p += C[k * NC + i] * C[k * NC + j];
    __shared__ float red[4][64];
    red[seg][i] = p;
    __syncthreads();
    if (seg == 0)
        gram[i * NC + j] = red[0][i] + red[1][i] + red[2][i] + red[3][i];
}

// ---------------- ginv = inv(gram), Gauss-Jordan (SPD, no pivoting) ----------------
__global__ __launch_bounds__(256) void k_inv(const float* __restrict__ gram,
                                             float* __restrict__ ginv) {
    __shared__ float A[64][128];
    int tid  = threadIdx.x;
    int row  = tid & 63;
    int half = tid >> 6;            // 0..3 -> 32-col strip
    for (int t = tid; t < 64 * 64; t += 256) {
        int r = t >> 6, c = t & 63;
        A[r][c]      = gram[t];
        A[r][c + 64] = (r == c) ? 1.f : 0.f;
    }
    __syncthreads();
    for (int p = 0; p < 64; ++p) {
        float piv = A[p][p];
        float f   = A[row][p];
        __syncthreads();
        float rp = 1.0f / piv;
        if (tid < 128) A[p][tid] *= rp;
        __syncthreads();
        if (row != p) {
            int c0 = half * 32;
            #pragma unroll 8
            for (int c = c0; c < c0 + 32; ++c)
                A[row][c] -= f * A[p][c];
        }
        __syncthreads();
    }
    for (int t = tid; t < 64 * 64; t += 256) {
        int r = t >> 6, c = t & 63;
        ginv[t] = A[r][c + 64];
    }
}

// ---------------- Dm = C @ Ginv  [768,64] ----------------
__global__ __launch_bounds__(256) void k_dmat(const float* __restrict__ C,
                                              const float* __restrict__ ginv,
                                              float* __restrict__ Dm) {
    int idx = blockIdx.x * 256 + threadIdx.x;   // 768*64
    int k = idx >> 6;
    int i = idx & 63;
    float acc = 0.f;
    #pragma unroll 8
    for (int j = 0; j < 64; ++j)
        acc += C[k * 64 + j] * ginv[j * 64 + i];
    Dm[idx] = acc;
}

// ---------------- V = Dm^T @ W_h  [64,1000] ----------------
__global__ __launch_bounds__(256) void k_vmat(const float* __restrict__ Dm,
                                              const float* __restrict__ W,
                                              float* __restrict__ V) {
    int i  = threadIdx.x & 63;
    int ns = threadIdx.x >> 6;
    int n  = blockIdx.x * 4 + ns;   // 250 blocks -> n in [0,1000)
    float acc = 0.f;
    for (int k = 0; k < DD; ++k)
        acc += Dm[k * 64 + i] * W[(size_t)k * NY + n];
    V[i * NY + n] = acc;
}

// ---------------- S = |cm @ C| / colnorm(C)  [500,64] ----------------
__global__ __launch_bounds__(256) void k_score(const float* __restrict__ cm,
                                               const float* __restrict__ C,
                                               const float* __restrict__ gram,
                                               float* __restrict__ S) {
    int r   = blockIdx.x;           // 0..499
    int c   = threadIdx.x & 63;
    int seg = threadIdx.x >> 6;
    const float* cmr = cm + (size_t)r * DD;
    float p = 0.f;
    for (int k = seg * 192; k < seg * 192 + 192; ++k)
        p += cmr[k] * C[k * 64 + c];
    __shared__ float red[4][64];
    red[seg][c] = p;
    __syncthreads();
    if (seg == 0) {
        float s   = fabsf(red[0][c] + red[1][c] + red[2][c] + red[3][c]);
        float nrm = fmaxf(sqrtf(gram[c * 64 + c]), EPSN);
        S[r * 64 + c] = s / nrm;
    }
}

// ---------------- L_sparse_1, L_sparse_2 from S ----------------
__global__ __launch_bounds__(256) void k_sparse(const float* __restrict__ S,
                                                float* __restrict__ out) {
    __shared__ float colred[4][64];
    __shared__ float rn[64];
    __shared__ float trc[64];
    __shared__ float r1[4], r2[4];
    int tid = threadIdx.x;
    int c = tid & 63, seg = tid >> 6;
    float p = 0.f;
    for (int r = seg; r < NCL; r += 4) {
        float v = S[r * 64 + c];
        p += v * v;
    }
    colred[seg][c] = p;
    __syncthreads();
    if (seg == 0) {
        float n2  = colred[0][c] + colred[1][c] + colred[2][c] + colred[3][c];
        float inv = 1.0f / fmaxf(sqrtf(n2), EPSN);
        rn[c]  = inv;
        trc[c] = n2 * inv * inv;
    }
    __syncthreads();
    float l1p = 0.f, l2p = 0.f;
    for (int r = tid; r < NCL; r += 256) {
        float rs = 0.f;
        #pragma unroll
        for (int cc = 0; cc < 64; ++cc)
            rs += S[r * 64 + cc] * rn[cc];
        l1p += rs;
        l2p += rs * rs;
    }
    #pragma unroll
    for (int off = 32; off > 0; off >>= 1) {
        l1p += __shfl_down(l1p, off);
        l2p += __shfl_down(l2p, off);
    }
    int wave = tid >> 6, lane = tid & 63;
    if (lane == 0) { r1[wave] = l1p; r2[wave] = l2p; }
    __syncthreads();
    if (tid == 0) {
        float L1 = r1[0] + r1[1] + r1[2] + r1[3];
        float L2 = r2[0] + r2[1] + r2[2] + r2[3];
        float tr = 0.f;
        #pragma unroll
        for (int cc = 0; cc < 64; ++cc) tr += trc[cc];
        out[0] = L1;
        out[1] = L2 - tr;
    }
}

// ---------------- T = X @ C  [8192,64], tile 32x64, K-chunk 64 ----------------
__global__ __launch_bounds__(256) void k_tmat(const float* __restrict__ X,
                                              const float* __restrict__ C,
                                              float* __restrict__ T) {
    __shared__ float Xs[32][68];    // pad 68: keeps 16B alignment, spreads banks
    __shared__ float Cs[64][64];
    int tid = threadIdx.x;
    int r0g = blockIdx.x * 32;
    int cx  = tid & 31;             // cols 2cx, 2cx+1
    int ry  = tid >> 5;             // rows ry*4 .. +3
    float acc[4][2] = {};
    for (int kc = 0; kc < DD; kc += 64) {
        __syncthreads();
        {   // stage X: 32 rows x 64 k
            int kq = tid & 7;
            int rr = tid >> 3;
            const float4* src = (const float4*)(X + (size_t)(r0g + rr) * DD + kc) + kq * 2;
            float4 a = src[0], b = src[1];
            *((float4*)&Xs[rr][kq * 8])     = a;
            *((float4*)&Xs[rr][kq * 8 + 4]) = b;
        }
        {   // stage C: 64 k x 64 c
            int c4 = tid & 15;
            int kk = tid >> 4;
            #pragma unroll
            for (int pass = 0; pass < 4; ++pass) {
                int k = kk + pass * 16;
                *((float4*)&Cs[k][c4 * 4]) =
                    *((const float4*)(C + (size_t)(kc + k) * 64 + c4 * 4));
            }
        }
        __syncthreads();
        #pragma unroll 4
        for (int k = 0; k < 64; ++k) {
            float b0 = Cs[k][cx * 2], b1 = Cs[k][cx * 2 + 1];
            #pragma unroll
            for (int r = 0; r < 4; ++r) {
                float a = Xs[ry * 4 + r][k];
                acc[r][0] += a * b0;
                acc[r][1] += a * b1;
            }
        }
    }
    #pragma unroll
    for (int r = 0; r < 4; ++r) {
        int row = r0g + ry * 4 + r;
        float2 v = {acc[r][0], acc[r][1]};
        *((float2*)(T + (size_t)row * 64 + cx * 2)) = v;
    }
}

// ---------------- y = T @ V + b  [8192,1000], tile 64x128 ----------------
__global__ __launch_bounds__(256) void k_ypred(const float* __restrict__ T,
                                               const float* __restrict__ V,
                                               const float* __restrict__ bh,
                                               float* __restrict__ Y) {
    __shared__ float Ts[64][68];    // transposed: Ts[k][row]
    __shared__ float Vs[64][128];
    int tid = threadIdx.x;
    int r0g = blockIdx.x * 64;
    int c0g = blockIdx.y * 128;
    {   // stage T transposed
        int kf = tid & 15;
        int rr = tid >> 4;
        #pragma unroll
        for (int pass = 0; pass < 4; ++pass) {
            int row = rr + pass * 16;
            float4 a = *((const float4*)(T + (size_t)(r0g + row) * 64 + kf * 4));
            Ts[kf * 4 + 0][row] = a.x;
            Ts[kf * 4 + 1][row] = a.y;
            Ts[kf * 4 + 2][row] = a.z;
            Ts[kf * 4 + 3][row] = a.w;
        }
    }
    {   // stage V (zero-pad cols >= 1000)
        int cf = tid & 31;
        int kk = tid >> 5;
        #pragma unroll
        for (int pass = 0; pass < 8; ++pass) {
            int k = kk + pass * 8;
            int c = c0g + cf * 4;
            float4 v = {0.f, 0.f, 0.f, 0.f};
            if (c < NY) v = *((const float4*)(V + (size_t)k * NY + c));
            *((float4*)&Vs[k][cf * 4]) = v;
        }
    }
    __syncthreads();
    int cx = tid & 15;              // cols cx*8 .. +8
    int ry = tid >> 4;              // rows ry*4 .. +4
    float acc[4][8] = {};
    #pragma unroll 2
    for (int k = 0; k < 64; ++k) {
        float4 a  = *((float4*)&Ts[k][ry * 4]);
        float4 b0 = *((float4*)&Vs[k][cx * 8]);
        float4 b1 = *((float4*)&Vs[k][cx * 8 + 4]);
        float av[4] = {a.x, a.y, a.z, a.w};
        float bv[8] = {b0.x, b0.y, b0.z, b0.w, b1.x, b1.y, b1.z, b1.w};
        #pragma unroll
        for (int r = 0; r < 4; ++r)
            #pragma unroll
            for (int c = 0; c < 8; ++c)
                acc[r][c] += av[r] * bv[c];
    }
    #pragma unroll
    for (int r = 0; r < 4; ++r) {
        int row   = r0g + ry * 4 + r;
        int cbase = c0g + cx * 8;
        #pragma unroll
        for (int cq = 0; cq < 2; ++cq) {
            int c = cbase + cq * 4;
            if (c < NY) {
                float4 o;
                o.x = acc[r][cq * 4 + 0] + bh[c + 0];
                o.y = acc[r][cq * 4 + 1] + bh[c + 1];
                o.z = acc[r][cq * 4 + 2] + bh[c + 2];
                o.w = acc[r][cq * 4 + 3] + bh[c + 3];
                *((float4*)(Y + (size_t)row * NY + c)) = o;
            }
        }
    }
}

extern "C" void kernel_launch(void* const* d_in, const int* in_sizes, int n_in,
                              void* d_out, int out_size, void* d_ws, size_t ws_size,
                              hipStream_t stream) {
    const float* X        = (const float*)d_in[0];   // [8192,768]
    const float* clusters = (const float*)d_in[1];   // [500,100,768]
    const float* C        = (const float*)d_in[2];   // [768,64]
    const float* W        = (const float*)d_in[3];   // [768,1000]
    const float* bh       = (const float*)d_in[4];   // [1000]
    float* out = (float*)d_out;                      // y_pred (8192*1000), L1, L2
    float* ws  = (float*)d_ws;

    float* cm   = ws;                 // 500*768   = 384000
    float* gram = cm   + 384000;      // 64*64     = 4096
    float* ginv = gram + 4096;        // 4096
    float* Dm   = ginv + 4096;        // 768*64    = 49152
    float* V    = Dm   + 49152;       // 64*1000   = 64000
    float* T    = V    + 64000;       // 8192*64   = 524288
    float* S    = T    + 524288;      // 500*64    = 32000
                                      // total ~4.25 MB of d_ws

    k_cmean <<<dim3(375),     dim3(256), 0, stream>>>(clusters, cm);
    k_gram  <<<dim3(64),      dim3(256), 0, stream>>>(C, gram);
    k_inv   <<<dim3(1),       dim3(256), 0, stream>>>(gram, ginv);
    k_dmat  <<<dim3(192),     dim3(256), 0, stream>>>(C, ginv, Dm);
    k_vmat  <<<dim3(250),     dim3(256), 0, stream>>>(Dm, W, V);
    k_score <<<dim3(500),     dim3(256), 0, stream>>>(cm, C, gram, S);
    k_sparse<<<dim3(1),       dim3(256), 0, stream>>>(S, out + (size_t)BS * NY);
    k_tmat  <<<dim3(256),     dim3(256), 0, stream>>>(X, C, T);
    k_ypred <<<dim3(128, 8),  dim3(256), 0, stream>>>(T, V, bh, out);
}

// Round 2
// 258.944 us; speedup vs baseline: 2.4527x; 2.4527x over previous
//
#include <hip/hip_runtime.h>
#include <math.h>

#define BS   8192
#define DD   768
#define NC   64
#define NCL  500
#define CS   100
#define NY   1000
#define EPSN 1e-12f

// ---------------- cluster_mean: [500,100,768] -> [500,768] ----------------
__global__ __launch_bounds__(256) void k_cmean(const float* __restrict__ clusters,
                                               float* __restrict__ cm) {
    int idx = blockIdx.x * 256 + threadIdx.x;          // over 500*768/4 float4s
    if (idx >= NCL * DD / 4) return;
    int r  = idx / (DD / 4);
    int d4 = idx % (DD / 4);
    const float4* base = (const float4*)(clusters + (size_t)r * CS * DD) + d4;
    float4 acc = {0.f, 0.f, 0.f, 0.f};
    for (int s = 0; s < CS; ++s) {
        float4 v = base[(size_t)s * (DD / 4)];
        acc.x += v.x; acc.y += v.y; acc.z += v.z; acc.w += v.w;
    }
    const float sc = 1.0f / CS;
    acc.x *= sc; acc.y *= sc; acc.z *= sc; acc.w *= sc;
    ((float4*)cm)[idx] = acc;
}

// ---------------- gram = C^T C  [64,64] ----------------
__global__ __launch_bounds__(256) void k_gram(const float* __restrict__ C,
                                              float* __restrict__ gram) {
    int j   = blockIdx.x;           // 0..63
    int i   = threadIdx.x & 63;
    int seg = threadIdx.x >> 6;     // 0..3
    float p = 0.f;
    for (int k = seg * 192; k < seg * 192 + 192; ++k)
        p += C[k * NC + i] * C[k * NC + j];
    __shared__ float red[4][64];
    red[seg][i] = p;
    __syncthreads();
    if (seg == 0)
        gram[i * NC + j] = red[0][i] + red[1][i] + red[2][i] + red[3][i];
}

// ---------------- ginv = inv(gram), Gauss-Jordan (SPD, no pivoting) ----------------
// R1 fix: row stride 129 (was 128). With stride%32==0 every wave access
// A[lane][c] hit one bank -> 64-way conflict -> 1.0M conflict cycles = 460us.
// Stride 129 gives bank (row+c)%32 -> 2-way (free, m136).
__global__ __launch_bounds__(256) void k_inv(const float* __restrict__ gram,
                                             float* __restrict__ ginv) {
    __shared__ float A[64][129];
    int tid  = threadIdx.x;
    int row  = tid & 63;
    int half = tid >> 6;            // 0..3 -> 32-col strip of the 128 live cols
    for (int t = tid; t < 64 * 64; t += 256) {
        int r = t >> 6, c = t & 63;
        A[r][c]      = gram[t];
        A[r][c + 64] = (r == c) ? 1.f : 0.f;
    }
    __syncthreads();
    for (int p = 0; p < 64; ++p) {
        float piv = A[p][p];
        float f   = A[row][p];
        __syncthreads();
        float rp = 1.0f / piv;
        if (tid < 128) A[p][tid] *= rp;
        __syncthreads();
        if (row != p) {
            int c0 = half * 32;
            #pragma unroll 8
            for (int c = c0; c < c0 + 32; ++c)
                A[row][c] -= f * A[p][c];
        }
        __syncthreads();
    }
    for (int t = tid; t < 64 * 64; t += 256) {
        int r = t >> 6, c = t & 63;
        ginv[t] = A[r][c + 64];
    }
}

// ---------------- Dm = C @ Ginv  [768,64] ----------------
__global__ __launch_bounds__(256) void k_dmat(const float* __restrict__ C,
                                              const float* __restrict__ ginv,
                                              float* __restrict__ Dm) {
    int idx = blockIdx.x * 256 + threadIdx.x;   // 768*64
    int k = idx >> 6;
    int i = idx & 63;
    float acc = 0.f;
    #pragma unroll 8
    for (int j = 0; j < 64; ++j)
        acc += C[k * 64 + j] * ginv[j * 64 + i];
    Dm[idx] = acc;
}

// ---------------- V = Dm^T @ W_h  [64,1000] ----------------
__global__ __launch_bounds__(256) void k_vmat(const float* __restrict__ Dm,
                                              const float* __restrict__ W,
                                              float* __restrict__ V) {
    int i  = threadIdx.x & 63;
    int ns = threadIdx.x >> 6;
    int n  = blockIdx.x * 4 + ns;   // 250 blocks -> n in [0,1000)
    float acc = 0.f;
    for (int k = 0; k < DD; ++k)
        acc += Dm[k * 64 + i] * W[(size_t)k * NY + n];
    V[i * NY + n] = acc;
}

// ---------------- S = |cm @ C| / colnorm(C)  [500,64] ----------------
__global__ __launch_bounds__(256) void k_score(const float* __restrict__ cm,
                                               const float* __restrict__ C,
                                               const float* __restrict__ gram,
                                               float* __restrict__ S) {
    int r   = blockIdx.x;           // 0..499
    int c   = threadIdx.x & 63;
    int seg = threadIdx.x >> 6;
    const float* cmr = cm + (size_t)r * DD;
    float p = 0.f;
    for (int k = seg * 192; k < seg * 192 + 192; ++k)
        p += cmr[k] * C[k * 64 + c];
    __shared__ float red[4][64];
    red[seg][c] = p;
    __syncthreads();
    if (seg == 0) {
        float s   = fabsf(red[0][c] + red[1][c] + red[2][c] + red[3][c]);
        float nrm = fmaxf(sqrtf(gram[c * 64 + c]), EPSN);
        S[r * 64 + c] = s / nrm;
    }
}

// ---------------- L_sparse_1, L_sparse_2 from S ----------------
__global__ __launch_bounds__(256) void k_sparse(const float* __restrict__ S,
                                                float* __restrict__ out) {
    __shared__ float colred[4][64];
    __shared__ float rn[64];
    __shared__ float trc[64];
    __shared__ float r1[4], r2[4];
    int tid = threadIdx.x;
    int c = tid & 63, seg = tid >> 6;
    float p = 0.f;
    for (int r = seg; r < NCL; r += 4) {
        float v = S[r * 64 + c];
        p += v * v;
    }
    colred[seg][c] = p;
    __syncthreads();
    if (seg == 0) {
        float n2  = colred[0][c] + colred[1][c] + colred[2][c] + colred[3][c];
        float inv = 1.0f / fmaxf(sqrtf(n2), EPSN);
        rn[c]  = inv;
        trc[c] = n2 * inv * inv;
    }
    __syncthreads();
    float l1p = 0.f, l2p = 0.f;
    for (int r = tid; r < NCL; r += 256) {
        float rs = 0.f;
        #pragma unroll
        for (int cc = 0; cc < 64; ++cc)
            rs += S[r * 64 + cc] * rn[cc];
        l1p += rs;
        l2p += rs * rs;
    }
    #pragma unroll
    for (int off = 32; off > 0; off >>= 1) {
        l1p += __shfl_down(l1p, off);
        l2p += __shfl_down(l2p, off);
    }
    int wave = tid >> 6, lane = tid & 63;
    if (lane == 0) { r1[wave] = l1p; r2[wave] = l2p; }
    __syncthreads();
    if (tid == 0) {
        float L1 = r1[0] + r1[1] + r1[2] + r1[3];
        float L2 = r2[0] + r2[1] + r2[2] + r2[3];
        float tr = 0.f;
        #pragma unroll
        for (int cc = 0; cc < 64; ++cc) tr += trc[cc];
        out[0] = L1;
        out[1] = L2 - tr;
    }
}

// ---------------- T = X @ C  [8192,64], tile 32x64, K-chunk 64 ----------------
__global__ __launch_bounds__(256) void k_tmat(const float* __restrict__ X,
                                              const float* __restrict__ C,
                                              float* __restrict__ T) {
    __shared__ float Xs[32][68];    // pad 68: keeps 16B alignment, spreads banks
    __shared__ float Cs[64][64];
    int tid = threadIdx.x;
    int r0g = blockIdx.x * 32;
    int cx  = tid & 31;             // cols 2cx, 2cx+1
    int ry  = tid >> 5;             // rows ry*4 .. +3
    float acc[4][2] = {};
    for (int kc = 0; kc < DD; kc += 64) {
        __syncthreads();
        {   // stage X: 32 rows x 64 k
            int kq = tid & 7;
            int rr = tid >> 3;
            const float4* src = (const float4*)(X + (size_t)(r0g + rr) * DD + kc) + kq * 2;
            float4 a = src[0], b = src[1];
            *((float4*)&Xs[rr][kq * 8])     = a;
            *((float4*)&Xs[rr][kq * 8 + 4]) = b;
        }
        {   // stage C: 64 k x 64 c
            int c4 = tid & 15;
            int kk = tid >> 4;
            #pragma unroll
            for (int pass = 0; pass < 4; ++pass) {
                int k = kk + pass * 16;
                *((float4*)&Cs[k][c4 * 4]) =
                    *((const float4*)(C + (size_t)(kc + k) * 64 + c4 * 4));
            }
        }
        __syncthreads();
        #pragma unroll 4
        for (int k = 0; k < 64; ++k) {
            float b0 = Cs[k][cx * 2], b1 = Cs[k][cx * 2 + 1];
            #pragma unroll
            for (int r = 0; r < 4; ++r) {
                float a = Xs[ry * 4 + r][k];
                acc[r][0] += a * b0;
                acc[r][1] += a * b1;
            }
        }
    }
    #pragma unroll
    for (int r = 0; r < 4; ++r) {
        int row = r0g + ry * 4 + r;
        float2 v = {acc[r][0], acc[r][1]};
        *((float2*)(T + (size_t)row * 64 + cx * 2)) = v;
    }
}

// ---------------- y = T @ V + b  [8192,1000], tile 64x128 ----------------
__global__ __launch_bounds__(256) void k_ypred(const float* __restrict__ T,
                                               const float* __restrict__ V,
                                               const float* __restrict__ bh,
                                               float* __restrict__ Y) {
    __shared__ float Ts[64][68];    // transposed: Ts[k][row]
    __shared__ float Vs[64][128];
    int tid = threadIdx.x;
    int r0g = blockIdx.x * 64;
    int c0g = blockIdx.y * 128;
    {   // stage T transposed
        int kf = tid & 15;
        int rr = tid >> 4;
        #pragma unroll
        for (int pass = 0; pass < 4; ++pass) {
            int row = rr + pass * 16;
            float4 a = *((const float4*)(T + (size_t)(r0g + row) * 64 + kf * 4));
            Ts[kf * 4 + 0][row] = a.x;
            Ts[kf * 4 + 1][row] = a.y;
            Ts[kf * 4 + 2][row] = a.z;
            Ts[kf * 4 + 3][row] = a.w;
        }
    }
    {   // stage V (zero-pad cols >= 1000)
        int cf = tid & 31;
        int kk = tid >> 5;
        #pragma unroll
        for (int pass = 0; pass < 8; ++pass) {
            int k = kk + pass * 8;
            int c = c0g + cf * 4;
            float4 v = {0.f, 0.f, 0.f, 0.f};
            if (c < NY) v = *((const float4*)(V + (size_t)k * NY + c));
            *((float4*)&Vs[k][cf * 4]) = v;
        }
    }
    __syncthreads();
    int cx = tid & 15;              // cols cx*8 .. +8
    int ry = tid >> 4;              // rows ry*4 .. +4
    float acc[4][8] = {};
    #pragma unroll 2
    for (int k = 0; k < 64; ++k) {
        float4 a  = *((float4*)&Ts[k][ry * 4]);
        float4 b0 = *((float4*)&Vs[k][cx * 8]);
        float4 b1 = *((float4*)&Vs[k][cx * 8 + 4]);
        float av[4] = {a.x, a.y, a.z, a.w};
        float bv[8] = {b0.x, b0.y, b0.z, b0.w, b1.x, b1.y, b1.z, b1.w};
        #pragma unroll
        for (int r = 0; r < 4; ++r)
            #pragma unroll
            for (int c = 0; c < 8; ++c)
                acc[r][c] += av[r] * bv[c];
    }
    #pragma unroll
    for (int r = 0; r < 4; ++r) {
        int row   = r0g + ry * 4 + r;
        int cbase = c0g + cx * 8;
        #pragma unroll
        for (int cq = 0; cq < 2; ++cq) {
            int c = cbase + cq * 4;
            if (c < NY) {
                float4 o;
                o.x = acc[r][cq * 4 + 0] + bh[c + 0];
                o.y = acc[r][cq * 4 + 1] + bh[c + 1];
                o.z = acc[r][cq * 4 + 2] + bh[c + 2];
                o.w = acc[r][cq * 4 + 3] + bh[c + 3];
                *((float4*)(Y + (size_t)row * NY + c)) = o;
            }
        }
    }
}

extern "C" void kernel_launch(void* const* d_in, const int* in_sizes, int n_in,
                              void* d_out, int out_size, void* d_ws, size_t ws_size,
                              hipStream_t stream) {
    const float* X        = (const float*)d_in[0];   // [8192,768]
    const float* clusters = (const float*)d_in[1];   // [500,100,768]
    const float* C        = (const float*)d_in[2];   // [768,64]
    const float* W        = (const float*)d_in[3];   // [768,1000]
    const float* bh       = (const float*)d_in[4];   // [1000]
    float* out = (float*)d_out;                      // y_pred (8192*1000), L1, L2
    float* ws  = (float*)d_ws;

    float* cm   = ws;                 // 500*768   = 384000
    float* gram = cm   + 384000;      // 64*64     = 4096
    float* ginv = gram + 4096;        // 4096
    float* Dm   = ginv + 4096;        // 768*64    = 49152
    float* V    = Dm   + 49152;       // 64*1000   = 64000
    float* T    = V    + 64000;       // 8192*64   = 524288
    float* S    = T    + 524288;      // 500*64    = 32000
                                      // total ~4.25 MB of d_ws

    k_cmean <<<dim3(375),     dim3(256), 0, stream>>>(clusters, cm);
    k_gram  <<<dim3(64),      dim3(256), 0, stream>>>(C, gram);
    k_inv   <<<dim3(1),       dim3(256), 0, stream>>>(gram, ginv);
    k_dmat  <<<dim3(192),     dim3(256), 0, stream>>>(C, ginv, Dm);
    k_vmat  <<<dim3(250),     dim3(256), 0, stream>>>(Dm, W, V);
    k_score <<<dim3(500),     dim3(256), 0, stream>>>(cm, C, gram, S);
    k_sparse<<<dim3(1),       dim3(256), 0, stream>>>(S, out + (size_t)BS * NY);
    k_tmat  <<<dim3(256),     dim3(256), 0, stream>>>(X, C, T);
    k_ypred <<<dim3(128, 8),  dim3(256), 0, stream>>>(T, V, bh, out);
}

// Round 3
// 230.983 us; speedup vs baseline: 2.7496x; 1.1210x over previous
//
#include <hip/hip_runtime.h>
#include <math.h>

#define BS   8192
#define DD   768
#define NC   64
#define NCL  500
#define CS   100
#define NY   1000
#define EPSN 1e-12f

// ---------------- cluster_mean: [500,100,768] -> [500,768] ----------------
__global__ __launch_bounds__(256) void k_cmean(const float* __restrict__ clusters,
                                               float* __restrict__ cm) {
    int idx = blockIdx.x * 256 + threadIdx.x;          // over 500*768/4 float4s
    if (idx >= NCL * DD / 4) return;
    int r  = idx / (DD / 4);
    int d4 = idx % (DD / 4);
    const float4* base = (const float4*)(clusters + (size_t)r * CS * DD) + d4;
    float4 acc = {0.f, 0.f, 0.f, 0.f};
    for (int s = 0; s < CS; ++s) {
        float4 v = base[(size_t)s * (DD / 4)];
        acc.x += v.x; acc.y += v.y; acc.z += v.z; acc.w += v.w;
    }
    const float sc = 1.0f / CS;
    acc.x *= sc; acc.y *= sc; acc.z *= sc; acc.w *= sc;
    ((float4*)cm)[idx] = acc;
}

// ---------------- gram = C^T C  [64,64] ----------------
__global__ __launch_bounds__(256) void k_gram(const float* __restrict__ C,
                                              float* __restrict__ gram) {
    int j   = blockIdx.x;           // 0..63
    int i   = threadIdx.x & 63;
    int seg = threadIdx.x >> 6;     // 0..3
    float p = 0.f;
    for (int k = seg * 192; k < seg * 192 + 192; ++k)
        p += C[k * NC + i] * C[k * NC + j];
    __shared__ float red[4][64];
    red[seg][i] = p;
    __syncthreads();
    if (seg == 0)
        gram[i * NC + j] = red[0][i] + red[1][i] + red[2][i] + red[3][i];
}

// ---------------- ginv = inv(gram) ----------------
// R2 post-mortem: LDS-GJ with 3 barriers/pivot was latency-bound (85us,
// VALUBusy ~7% of its CU, 0 conflicts). R3: register-resident GJ.
// Thread (q=tid>>6, c=tid&63) holds rows q*16..q*16+15 of column c in
// registers (compile-time indexed). Per pivot: owning wave extracts+scales
// pivot row (uniform selects), publishes via parity-double-buffered LDS
// line -> ONE barrier/pivot; A[r][p] broadcast via intra-wave __shfl.
__global__ __launch_bounds__(256) void k_inv(const float* __restrict__ gram,
                                             float* __restrict__ ginv) {
    int t = threadIdx.x;
    int c = t & 63;
    int q = t >> 6;                  // wave id = row quarter (rows q*16..+15)
    float a[16], b[16];
    #pragma unroll
    for (int i = 0; i < 16; ++i) {
        int r = q * 16 + i;
        a[i] = gram[r * 64 + c];
        b[i] = (r == c) ? 1.f : 0.f;
    }
    __shared__ float asr[2][64];
    __shared__ float bsr[2][64];
    for (int p = 0; p < 64; ++p) {
        int qp  = p >> 4;
        int lp  = p & 15;
        int par = p & 1;
        if (q == qp) {
            float ap = 0.f, bp = 0.f;
            #pragma unroll
            for (int i = 0; i < 16; ++i) {
                if (i == lp) { ap = a[i]; bp = b[i]; }   // uniform select
            }
            float App = __shfl(ap, p);   // A[p][p]
            float s   = 1.0f / App;      // SPD, well-conditioned: no pivoting
            asr[par][c] = ap * s;        // scaled pivot row A[p][c]/App
            bsr[par][c] = bp * s;
        }
        __syncthreads();                 // single barrier per pivot
        float as_ = asr[par][c];
        float bs_ = bsr[par][c];
        #pragma unroll
        for (int i = 0; i < 16; ++i) {
            float f = __shfl(a[i], p);   // A[q*16+i][p] from lane p (pre-update)
            bool isp = (q == qp) && (i == lp);
            a[i] = isp ? as_ : fmaf(-f, as_, a[i]);
            b[i] = isp ? bs_ : fmaf(-f, bs_, b[i]);
        }
        // anti-dep on asr handled by parity double-buffer: write(p+2) to the
        // same buffer happens after barrier(p+1) > all reads(p).
    }
    #pragma unroll
    for (int i = 0; i < 16; ++i)
        ginv[(q * 16 + i) * 64 + c] = b[i];   // coalesced
}

// ---------------- Dm = C @ Ginv  [768,64] ----------------
__global__ __launch_bounds__(256) void k_dmat(const float* __restrict__ C,
                                              const float* __restrict__ ginv,
                                              float* __restrict__ Dm) {
    int idx = blockIdx.x * 256 + threadIdx.x;   // 768*64
    int k = idx >> 6;
    int i = idx & 63;
    float acc = 0.f;
    #pragma unroll 8
    for (int j = 0; j < 64; ++j)
        acc += C[k * 64 + j] * ginv[j * 64 + i];
    Dm[idx] = acc;
}

// ---------------- V = Dm^T @ W_h  [64,1000] ----------------
__global__ __launch_bounds__(256) void k_vmat(const float* __restrict__ Dm,
                                              const float* __restrict__ W,
                                              float* __restrict__ V) {
    int i  = threadIdx.x & 63;
    int ns = threadIdx.x >> 6;
    int n  = blockIdx.x * 4 + ns;   // 250 blocks -> n in [0,1000)
    float acc = 0.f;
    for (int k = 0; k < DD; ++k)
        acc += Dm[k * 64 + i] * W[(size_t)k * NY + n];
    V[i * NY + n] = acc;
}

// ---------------- S = |cm @ C| / colnorm(C)  [500,64] ----------------
__global__ __launch_bounds__(256) void k_score(const float* __restrict__ cm,
                                               const float* __restrict__ C,
                                               const float* __restrict__ gram,
                                               float* __restrict__ S) {
    int r   = blockIdx.x;           // 0..499
    int c   = threadIdx.x & 63;
    int seg = threadIdx.x >> 6;
    const float* cmr = cm + (size_t)r * DD;
    float p = 0.f;
    for (int k = seg * 192; k < seg * 192 + 192; ++k)
        p += cmr[k] * C[k * 64 + c];
    __shared__ float red[4][64];
    red[seg][c] = p;
    __syncthreads();
    if (seg == 0) {
        float s   = fabsf(red[0][c] + red[1][c] + red[2][c] + red[3][c]);
        float nrm = fmaxf(sqrtf(gram[c * 64 + c]), EPSN);
        S[r * 64 + c] = s / nrm;
    }
}

// ---------------- L_sparse_1, L_sparse_2 from S ----------------
__global__ __launch_bounds__(256) void k_sparse(const float* __restrict__ S,
                                                float* __restrict__ out) {
    __shared__ float colred[4][64];
    __shared__ float rn[64];
    __shared__ float trc[64];
    __shared__ float r1[4], r2[4];
    int tid = threadIdx.x;
    int c = tid & 63, seg = tid >> 6;
    float p = 0.f;
    for (int r = seg; r < NCL; r += 4) {
        float v = S[r * 64 + c];
        p += v * v;
    }
    colred[seg][c] = p;
    __syncthreads();
    if (seg == 0) {
        float n2  = colred[0][c] + colred[1][c] + colred[2][c] + colred[3][c];
        float inv = 1.0f / fmaxf(sqrtf(n2), EPSN);
        rn[c]  = inv;
        trc[c] = n2 * inv * inv;
    }
    __syncthreads();
    float l1p = 0.f, l2p = 0.f;
    for (int r = tid; r < NCL; r += 256) {
        float rs = 0.f;
        #pragma unroll
        for (int cc = 0; cc < 64; ++cc)
            rs += S[r * 64 + cc] * rn[cc];
        l1p += rs;
        l2p += rs * rs;
    }
    #pragma unroll
    for (int off = 32; off > 0; off >>= 1) {
        l1p += __shfl_down(l1p, off);
        l2p += __shfl_down(l2p, off);
    }
    int wave = tid >> 6, lane = tid & 63;
    if (lane == 0) { r1[wave] = l1p; r2[wave] = l2p; }
    __syncthreads();
    if (tid == 0) {
        float L1 = r1[0] + r1[1] + r1[2] + r1[3];
        float L2 = r2[0] + r2[1] + r2[2] + r2[3];
        float tr = 0.f;
        #pragma unroll
        for (int cc = 0; cc < 64; ++cc) tr += trc[cc];
        out[0] = L1;
        out[1] = L2 - tr;
    }
}

// ---------------- T = X @ C  [8192,64], tile 32x64, K-chunk 64 ----------------
__global__ __launch_bounds__(256) void k_tmat(const float* __restrict__ X,
                                              const float* __restrict__ C,
                                              float* __restrict__ T) {
    __shared__ float Xs[32][68];    // pad 68: keeps 16B alignment, spreads banks
    __shared__ float Cs[64][64];
    int tid = threadIdx.x;
    int r0g = blockIdx.x * 32;
    int cx  = tid & 31;             // cols 2cx, 2cx+1
    int ry  = tid >> 5;             // rows ry*4 .. +3
    float acc[4][2] = {};
    for (int kc = 0; kc < DD; kc += 64) {
        __syncthreads();
        {   // stage X: 32 rows x 64 k
            int kq = tid & 7;
            int rr = tid >> 3;
            const float4* src = (const float4*)(X + (size_t)(r0g + rr) * DD + kc) + kq * 2;
            float4 a = src[0], b = src[1];
            *((float4*)&Xs[rr][kq * 8])     = a;
            *((float4*)&Xs[rr][kq * 8 + 4]) = b;
        }
        {   // stage C: 64 k x 64 c
            int c4 = tid & 15;
            int kk = tid >> 4;
            #pragma unroll
            for (int pass = 0; pass < 4; ++pass) {
                int k = kk + pass * 16;
                *((float4*)&Cs[k][c4 * 4]) =
                    *((const float4*)(C + (size_t)(kc + k) * 64 + c4 * 4));
            }
        }
        __syncthreads();
        #pragma unroll 4
        for (int k = 0; k < 64; ++k) {
            float b0 = Cs[k][cx * 2], b1 = Cs[k][cx * 2 + 1];
            #pragma unroll
            for (int r = 0; r < 4; ++r) {
                float a = Xs[ry * 4 + r][k];
                acc[r][0] += a * b0;
                acc[r][1] += a * b1;
            }
        }
    }
    #pragma unroll
    for (int r = 0; r < 4; ++r) {
        int row = r0g + ry * 4 + r;
        float2 v = {acc[r][0], acc[r][1]};
        *((float2*)(T + (size_t)row * 64 + cx * 2)) = v;
    }
}

// ---------------- y = T @ V + b  [8192,1000], tile 64x128 ----------------
__global__ __launch_bounds__(256) void k_ypred(const float* __restrict__ T,
                                               const float* __restrict__ V,
                                               const float* __restrict__ bh,
                                               float* __restrict__ Y) {
    __shared__ float Ts[64][68];    // transposed: Ts[k][row]
    __shared__ float Vs[64][128];
    int tid = threadIdx.x;
    int r0g = blockIdx.x * 64;
    int c0g = blockIdx.y * 128;
    {   // stage T transposed
        int kf = tid & 15;
        int rr = tid >> 4;
        #pragma unroll
        for (int pass = 0; pass < 4; ++pass) {
            int row = rr + pass * 16;
            float4 a = *((const float4*)(T + (size_t)(r0g + row) * 64 + kf * 4));
            Ts[kf * 4 + 0][row] = a.x;
            Ts[kf * 4 + 1][row] = a.y;
            Ts[kf * 4 + 2][row] = a.z;
            Ts[kf * 4 + 3][row] = a.w;
        }
    }
    {   // stage V (zero-pad cols >= 1000)
        int cf = tid & 31;
        int kk = tid >> 5;
        #pragma unroll
        for (int pass = 0; pass < 8; ++pass) {
            int k = kk + pass * 8;
            int c = c0g + cf * 4;
            float4 v = {0.f, 0.f, 0.f, 0.f};
            if (c < NY) v = *((const float4*)(V + (size_t)k * NY + c));
            *((float4*)&Vs[k][cf * 4]) = v;
        }
    }
    __syncthreads();
    int cx = tid & 15;              // cols cx*8 .. +8
    int ry = tid >> 4;              // rows ry*4 .. +4
    float acc[4][8] = {};
    #pragma unroll 2
    for (int k = 0; k < 64; ++k) {
        float4 a  = *((float4*)&Ts[k][ry * 4]);
        float4 b0 = *((float4*)&Vs[k][cx * 8]);
        float4 b1 = *((float4*)&Vs[k][cx * 8 + 4]);
        float av[4] = {a.x, a.y, a.z, a.w};
        float bv[8] = {b0.x, b0.y, b0.z, b0.w, b1.x, b1.y, b1.z, b1.w};
        #pragma unroll
        for (int r = 0; r < 4; ++r)
            #pragma unroll
            for (int c = 0; c < 8; ++c)
                acc[r][c] += av[r] * bv[c];
    }
    #pragma unroll
    for (int r = 0; r < 4; ++r) {
        int row   = r0g + ry * 4 + r;
        int cbase = c0g + cx * 8;
        #pragma unroll
        for (int cq = 0; cq < 2; ++cq) {
            int c = cbase + cq * 4;
            if (c < NY) {
                float4 o;
                o.x = acc[r][cq * 4 + 0] + bh[c + 0];
                o.y = acc[r][cq * 4 + 1] + bh[c + 1];
                o.z = acc[r][cq * 4 + 2] + bh[c + 2];
                o.w = acc[r][cq * 4 + 3] + bh[c + 3];
                *((float4*)(Y + (size_t)row * NY + c)) = o;
            }
        }
    }
}

extern "C" void kernel_launch(void* const* d_in, const int* in_sizes, int n_in,
                              void* d_out, int out_size, void* d_ws, size_t ws_size,
                              hipStream_t stream) {
    const float* X        = (const float*)d_in[0];   // [8192,768]
    const float* clusters = (const float*)d_in[1];   // [500,100,768]
    const float* C        = (const float*)d_in[2];   // [768,64]
    const float* W        = (const float*)d_in[3];   // [768,1000]
    const float* bh       = (const float*)d_in[4];   // [1000]
    float* out = (float*)d_out;                      // y_pred (8192*1000), L1, L2
    float* ws  = (float*)d_ws;

    float* cm   = ws;                 // 500*768   = 384000
    float* gram = cm   + 384000;      // 64*64     = 4096
    float* ginv = gram + 4096;        // 4096
    float* Dm   = ginv + 4096;        // 768*64    = 49152
    float* V    = Dm   + 49152;       // 64*1000   = 64000
    float* T    = V    + 64000;       // 8192*64   = 524288
    float* S    = T    + 524288;      // 500*64    = 32000
                                      // total ~4.25 MB of d_ws

    k_cmean <<<dim3(375),     dim3(256), 0, stream>>>(clusters, cm);
    k_gram  <<<dim3(64),      dim3(256), 0, stream>>>(C, gram);
    k_inv   <<<dim3(1),       dim3(256), 0, stream>>>(gram, ginv);
    k_dmat  <<<dim3(192),     dim3(256), 0, stream>>>(C, ginv, Dm);
    k_vmat  <<<dim3(250),     dim3(256), 0, stream>>>(Dm, W, V);
    k_score <<<dim3(500),     dim3(256), 0, stream>>>(cm, C, gram, S);
    k_sparse<<<dim3(1),       dim3(256), 0, stream>>>(S, out + (size_t)BS * NY);
    k_tmat  <<<dim3(256),     dim3(256), 0, stream>>>(X, C, T);
    k_ypred <<<dim3(128, 8),  dim3(256), 0, stream>>>(T, V, bh, out);
}

// Round 4
// 196.576 us; speedup vs baseline: 3.2308x; 1.1750x over previous
//
#include <hip/hip_runtime.h>
#include <math.h>

#define BS   8192
#define DD   768
#define NC   64
#define NCL  500
#define CS   100
#define NY   1000
#define EPSN 1e-12f

#define NB_CMEAN 375
#define NB_GRAM  64
#define NB_U     16
#define NB_TMAT  256
#define NB_A     (NB_CMEAN + NB_GRAM + NB_U + NB_TMAT)

// ============ PHASE A: cmean || gram || U = C^T W || T = X C ============
// All four are mutually independent. cmean saturates HBM (153.6 MB);
// gram/U/tmat are VALU/LDS-bound and hide under it. One shared-mem union.
__global__ __launch_bounds__(256) void k_phaseA(
    const float* __restrict__ clusters, const float* __restrict__ C,
    const float* __restrict__ W, const float* __restrict__ X,
    float* __restrict__ cm, float* __restrict__ gram,
    float* __restrict__ U, float* __restrict__ T) {
    __shared__ __align__(16) char smem_raw[34816];
    int b   = blockIdx.x;
    int tid = threadIdx.x;

    if (b < NB_CMEAN) {
        // ---- cluster_mean: [500,100,768] -> [500,768], float4 streaming ----
        int idx = b * 256 + tid;                 // 375*256 == 500*768/4 exactly
        int r  = idx / (DD / 4);
        int d4 = idx % (DD / 4);
        const float4* base = (const float4*)(clusters + (size_t)r * CS * DD) + d4;
        float4 acc = {0.f, 0.f, 0.f, 0.f};
        for (int s = 0; s < CS; ++s) {
            float4 v = base[(size_t)s * (DD / 4)];
            acc.x += v.x; acc.y += v.y; acc.z += v.z; acc.w += v.w;
        }
        const float sc = 1.0f / CS;
        acc.x *= sc; acc.y *= sc; acc.z *= sc; acc.w *= sc;
        ((float4*)cm)[idx] = acc;
    } else if (b < NB_CMEAN + NB_GRAM) {
        // ---- gram = C^T C [64,64] ----
        int j   = b - NB_CMEAN;
        int i   = tid & 63;
        int seg = tid >> 6;
        float p = 0.f;
        for (int k = seg * 192; k < seg * 192 + 192; ++k)
            p += C[k * NC + i] * C[k * NC + j];
        float (*red)[64] = (float(*)[64])smem_raw;
        red[seg][i] = p;
        __syncthreads();
        if (seg == 0)
            gram[i * NC + j] = red[0][i] + red[1][i] + red[2][i] + red[3][i];
    } else if (b < NB_CMEAN + NB_GRAM + NB_U) {
        // ---- U = C^T W [64,1000], 64x64 tile, K-chunk 64 ----
        int nt = b - (NB_CMEAN + NB_GRAM);
        int n0 = nt * 64;
        float (*Csh)[68] = (float(*)[68])smem_raw;              // [k][i]
        float (*Wsh)[68] = (float(*)[68])(smem_raw + 64 * 68 * 4); // [k][n]
        int iq = tid & 15;
        int nq = tid >> 4;
        float acc[4][4] = {};
        for (int kc = 0; kc < DD; kc += 64) {
            __syncthreads();
            {   // stage C chunk
                int i4 = tid & 15, kk = tid >> 4;
                #pragma unroll
                for (int pass = 0; pass < 4; ++pass) {
                    int k = kk + pass * 16;
                    *((float4*)&Csh[k][i4 * 4]) =
                        *((const float4*)(C + (size_t)(kc + k) * 64 + i4 * 4));
                }
            }
            {   // stage W chunk (zero-pad n >= 1000)
                int n4 = tid & 15, kk = tid >> 4;
                #pragma unroll
                for (int pass = 0; pass < 4; ++pass) {
                    int k = kk + pass * 16;
                    int n = n0 + n4 * 4;
                    float4 v = {0.f, 0.f, 0.f, 0.f};
                    if (n < NY)
                        v = *((const float4*)(W + (size_t)(kc + k) * NY + n));
                    *((float4*)&Wsh[k][n4 * 4]) = v;
                }
            }
            __syncthreads();
            #pragma unroll 4
            for (int k = 0; k < 64; ++k) {
                float4 a = *((float4*)&Csh[k][iq * 4]);
                float4 w = *((float4*)&Wsh[k][nq * 4]);
                float av[4] = {a.x, a.y, a.z, a.w};
                float wv[4] = {w.x, w.y, w.z, w.w};
                #pragma unroll
                for (int ii = 0; ii < 4; ++ii)
                    #pragma unroll
                    for (int nn = 0; nn < 4; ++nn)
                        acc[ii][nn] += av[ii] * wv[nn];
            }
        }
        int n = n0 + nq * 4;
        if (n < NY) {
            #pragma unroll
            for (int ii = 0; ii < 4; ++ii) {
                int i = iq * 4 + ii;
                float4 o = {acc[ii][0], acc[ii][1], acc[ii][2], acc[ii][3]};
                *((float4*)(U + (size_t)i * NY + n)) = o;
            }
        }
    } else {
        // ---- T = X @ C [8192,64], 32-row tile, K-chunk 64 (verified body) ----
        int blk = b - (NB_CMEAN + NB_GRAM + NB_U);
        float (*Xs)[68] = (float(*)[68])smem_raw;                 // [32][68]
        float (*Cs)[64] = (float(*)[64])(smem_raw + 32 * 68 * 4); // [64][64]
        int r0g = blk * 32;
        int cx  = tid & 31;
        int ry  = tid >> 5;
        float acc[4][2] = {};
        for (int kc = 0; kc < DD; kc += 64) {
            __syncthreads();
            {   // stage X
                int kq = tid & 7;
                int rr = tid >> 3;
                const float4* src = (const float4*)(X + (size_t)(r0g + rr) * DD + kc) + kq * 2;
                float4 a = src[0], c4v = src[1];
                *((float4*)&Xs[rr][kq * 8])     = a;
                *((float4*)&Xs[rr][kq * 8 + 4]) = c4v;
            }
            {   // stage C
                int c4 = tid & 15;
                int kk = tid >> 4;
                #pragma unroll
                for (int pass = 0; pass < 4; ++pass) {
                    int k = kk + pass * 16;
                    *((float4*)&Cs[k][c4 * 4]) =
                        *((const float4*)(C + (size_t)(kc + k) * 64 + c4 * 4));
                }
            }
            __syncthreads();
            #pragma unroll 4
            for (int k = 0; k < 64; ++k) {
                float b0 = Cs[k][cx * 2], b1 = Cs[k][cx * 2 + 1];
                #pragma unroll
                for (int r = 0; r < 4; ++r) {
                    float a = Xs[ry * 4 + r][k];
                    acc[r][0] += a * b0;
                    acc[r][1] += a * b1;
                }
            }
        }
        #pragma unroll
        for (int r = 0; r < 4; ++r) {
            int row = r0g + ry * 4 + r;
            float2 v = {acc[r][0], acc[r][1]};
            *((float2*)(T + (size_t)row * 64 + cx * 2)) = v;
        }
    }
}

// ============ PHASE B: inv (block 0) || score (blocks 1..500) ============
__global__ __launch_bounds__(256) void k_phaseB(
    const float* __restrict__ gram, const float* __restrict__ cm,
    const float* __restrict__ C, float* __restrict__ ginv,
    float* __restrict__ S) {
    int b   = blockIdx.x;
    int tid = threadIdx.x;
    if (b == 0) {
        // register-resident Gauss-Jordan (R3 body, verified)
        int c = tid & 63;
        int q = tid >> 6;
        float a[16], bb[16];
        #pragma unroll
        for (int i = 0; i < 16; ++i) {
            int r = q * 16 + i;
            a[i]  = gram[r * 64 + c];
            bb[i] = (r == c) ? 1.f : 0.f;
        }
        __shared__ float asr[2][64];
        __shared__ float bsr[2][64];
        for (int p = 0; p < 64; ++p) {
            int qp  = p >> 4;
            int lp  = p & 15;
            int par = p & 1;
            if (q == qp) {
                float ap = 0.f, bp = 0.f;
                #pragma unroll
                for (int i = 0; i < 16; ++i)
                    if (i == lp) { ap = a[i]; bp = bb[i]; }
                float App = __shfl(ap, p);
                float s   = 1.0f / App;
                asr[par][c] = ap * s;
                bsr[par][c] = bp * s;
            }
            __syncthreads();
            float as_ = asr[par][c];
            float bs_ = bsr[par][c];
            #pragma unroll
            for (int i = 0; i < 16; ++i) {
                float f = __shfl(a[i], p);
                bool isp = (q == qp) && (i == lp);
                a[i]  = isp ? as_ : fmaf(-f, as_, a[i]);
                bb[i] = isp ? bs_ : fmaf(-f, bs_, bb[i]);
            }
        }
        #pragma unroll
        for (int i = 0; i < 16; ++i)
            ginv[(q * 16 + i) * 64 + c] = bb[i];
    } else {
        // score: S = |cm @ C| / colnorm(C)
        int r   = b - 1;
        int c   = tid & 63;
        int seg = tid >> 6;
        const float* cmr = cm + (size_t)r * DD;
        float p = 0.f;
        for (int k = seg * 192; k < seg * 192 + 192; ++k)
            p += cmr[k] * C[k * 64 + c];
        __shared__ float red[4][64];
        red[seg][c] = p;
        __syncthreads();
        if (seg == 0) {
            float s   = fabsf(red[0][c] + red[1][c] + red[2][c] + red[3][c]);
            float nrm = fmaxf(sqrtf(gram[c * 64 + c]), EPSN);
            S[r * 64 + c] = s / nrm;
        }
    }
}

// ============ PHASE C: V = Ginv @ U (blocks 0..63) || sparse (block 64) ============
__global__ __launch_bounds__(256) void k_phaseC(
    const float* __restrict__ ginv, const float* __restrict__ U,
    const float* __restrict__ S, float* __restrict__ V,
    float* __restrict__ out2) {
    int b   = blockIdx.x;
    int tid = threadIdx.x;
    if (b < 64) {
        int i = b;
        float acc[4] = {0.f, 0.f, 0.f, 0.f};
        for (int j = 0; j < 64; ++j) {
            float g = ginv[i * 64 + j];          // block-uniform -> s_load
            #pragma unroll
            for (int q = 0; q < 4; ++q) {
                int n = tid + q * 256;
                if (n < NY) acc[q] = fmaf(g, U[(size_t)j * NY + n], acc[q]);
            }
        }
        #pragma unroll
        for (int q = 0; q < 4; ++q) {
            int n = tid + q * 256;
            if (n < NY) V[(size_t)i * NY + n] = acc[q];
        }
    } else {
        // sparse losses from S
        __shared__ float colred[4][64];
        __shared__ float rn[64];
        __shared__ float trc[64];
        __shared__ float r1[4], r2[4];
        int c = tid & 63, seg = tid >> 6;
        float p = 0.f;
        for (int r = seg; r < NCL; r += 4) {
            float v = S[r * 64 + c];
            p += v * v;
        }
        colred[seg][c] = p;
        __syncthreads();
        if (seg == 0) {
            float n2  = colred[0][c] + colred[1][c] + colred[2][c] + colred[3][c];
            float inv = 1.0f / fmaxf(sqrtf(n2), EPSN);
            rn[c]  = inv;
            trc[c] = n2 * inv * inv;
        }
        __syncthreads();
        float l1p = 0.f, l2p = 0.f;
        for (int r = tid; r < NCL; r += 256) {
            float rs = 0.f;
            #pragma unroll
            for (int cc = 0; cc < 64; ++cc)
                rs += S[r * 64 + cc] * rn[cc];
            l1p += rs;
            l2p += rs * rs;
        }
        #pragma unroll
        for (int off = 32; off > 0; off >>= 1) {
            l1p += __shfl_down(l1p, off);
            l2p += __shfl_down(l2p, off);
        }
        int wave = tid >> 6, lane = tid & 63;
        if (lane == 0) { r1[wave] = l1p; r2[wave] = l2p; }
        __syncthreads();
        if (tid == 0) {
            float L1 = r1[0] + r1[1] + r1[2] + r1[3];
            float L2 = r2[0] + r2[1] + r2[2] + r2[3];
            float tr = 0.f;
            #pragma unroll
            for (int cc = 0; cc < 64; ++cc) tr += trc[cc];
            out2[0] = L1;
            out2[1] = L2 - tr;
        }
    }
}

// ============ PHASE D: y = T @ V + b [8192,1000], tile 64x128 ============
__global__ __launch_bounds__(256) void k_ypred(const float* __restrict__ T,
                                               const float* __restrict__ V,
                                               const float* __restrict__ bh,
                                               float* __restrict__ Y) {
    __shared__ float Ts[64][68];    // transposed: Ts[k][row]
    __shared__ float Vs[64][128];
    int tid = threadIdx.x;
    int r0g = blockIdx.x * 64;
    int c0g = blockIdx.y * 128;
    {   // stage T transposed
        int kf = tid & 15;
        int rr = tid >> 4;
        #pragma unroll
        for (int pass = 0; pass < 4; ++pass) {
            int row = rr + pass * 16;
            float4 a = *((const float4*)(T + (size_t)(r0g + row) * 64 + kf * 4));
            Ts[kf * 4 + 0][row] = a.x;
            Ts[kf * 4 + 1][row] = a.y;
            Ts[kf * 4 + 2][row] = a.z;
            Ts[kf * 4 + 3][row] = a.w;
        }
    }
    {   // stage V (zero-pad cols >= 1000)
        int cf = tid & 31;
        int kk = tid >> 5;
        #pragma unroll
        for (int pass = 0; pass < 8; ++pass) {
            int k = kk + pass * 8;
            int c = c0g + cf * 4;
            float4 v = {0.f, 0.f, 0.f, 0.f};
            if (c < NY) v = *((const float4*)(V + (size_t)k * NY + c));
            *((float4*)&Vs[k][cf * 4]) = v;
        }
    }
    __syncthreads();
    int cx = tid & 15;
    int ry = tid >> 4;
    float acc[4][8] = {};
    #pragma unroll 2
    for (int k = 0; k < 64; ++k) {
        float4 a  = *((float4*)&Ts[k][ry * 4]);
        float4 b0 = *((float4*)&Vs[k][cx * 8]);
        float4 b1 = *((float4*)&Vs[k][cx * 8 + 4]);
        float av[4] = {a.x, a.y, a.z, a.w};
        float bv[8] = {b0.x, b0.y, b0.z, b0.w, b1.x, b1.y, b1.z, b1.w};
        #pragma unroll
        for (int r = 0; r < 4; ++r)
            #pragma unroll
            for (int c = 0; c < 8; ++c)
                acc[r][c] += av[r] * bv[c];
    }
    #pragma unroll
    for (int r = 0; r < 4; ++r) {
        int row   = r0g + ry * 4 + r;
        int cbase = c0g + cx * 8;
        #pragma unroll
        for (int cq = 0; cq < 2; ++cq) {
            int c = cbase + cq * 4;
            if (c < NY) {
                float4 o;
                o.x = acc[r][cq * 4 + 0] + bh[c + 0];
                o.y = acc[r][cq * 4 + 1] + bh[c + 1];
                o.z = acc[r][cq * 4 + 2] + bh[c + 2];
                o.w = acc[r][cq * 4 + 3] + bh[c + 3];
                *((float4*)(Y + (size_t)row * NY + c)) = o;
            }
        }
    }
}

extern "C" void kernel_launch(void* const* d_in, const int* in_sizes, int n_in,
                              void* d_out, int out_size, void* d_ws, size_t ws_size,
                              hipStream_t stream) {
    const float* X        = (const float*)d_in[0];   // [8192,768]
    const float* clusters = (const float*)d_in[1];   // [500,100,768]
    const float* C        = (const float*)d_in[2];   // [768,64]
    const float* W        = (const float*)d_in[3];   // [768,1000]
    const float* bh       = (const float*)d_in[4];   // [1000]
    float* out = (float*)d_out;                      // y_pred, L1, L2
    float* ws  = (float*)d_ws;

    float* cm   = ws;                 // 500*768   = 384000
    float* gram = cm   + 384000;      // 4096
    float* ginv = gram + 4096;        // 4096
    float* U    = ginv + 4096;        // 64*1000   = 64000
    float* V    = U    + 64000;       // 64*1000   = 64000
    float* T    = V    + 64000;       // 8192*64   = 524288
    float* S    = T    + 524288;      // 500*64    = 32000

    k_phaseA<<<dim3(NB_A),    dim3(256), 0, stream>>>(clusters, C, W, X, cm, gram, U, T);
    k_phaseB<<<dim3(501),     dim3(256), 0, stream>>>(gram, cm, C, ginv, S);
    k_phaseC<<<dim3(65),      dim3(256), 0, stream>>>(ginv, U, S, V, out + (size_t)BS * NY);
    k_ypred <<<dim3(128, 8),  dim3(256), 0, stream>>>(T, V, bh, out);
}